// Round 4
// baseline (886.831 us; speedup 1.0000x reference)
//
#include <hip/hip_runtime.h>
#include <hip/hip_bf16.h>
#include <math.h>

// Problem constants
#define N1R 65536   // B*N1 query rows
#define N2R 16384   // B*N2 point rows
#define NPB 4096    // N2 per batch
#define CC  256     // COUT
#define CHUNK 1024  // KNN LDS chunk (points)

typedef __attribute__((ext_vector_type(4))) float v4f;
typedef __attribute__((ext_vector_type(8))) short v8s;

static __device__ __forceinline__ short f2bs(float f) {
    union { __hip_bfloat16 h; short s; } u;
    u.h = __float2bfloat16(f);
    return u.s;
}

// ---------------------------------------------------------------------------
// GEMM: Y = X(n x Kdim, fp32) @ W(Kdim x 256, fp32) + bias, store fp32.
// fp32 -> bf16 on the fly; one wave computes one 16x16 tile via
// mfma_f32_16x16x32_bf16 (fp32 accumulate).
// A-frag: m = lane&15, k = (lane>>4)*8 + j
// B-frag: n = lane&15, k = (lane>>4)*8 + j
// D:      col n = lane&15, row m = (lane>>4)*4 + reg
// ---------------------------------------------------------------------------
__global__ __launch_bounds__(256)
void gemm_bias_kernel(const float* __restrict__ X,
                      const float* __restrict__ W,
                      const float* __restrict__ bias,
                      float* __restrict__ Y,
                      int Kdim)
{
    const int wave = (blockIdx.x << 2) + (threadIdx.x >> 6);
    const int lane = threadIdx.x & 63;
    const int tile_m = wave >> 4;        // 16 column tiles (256/16)
    const int tile_n = wave & 15;
    const int m0 = tile_m << 4, n0 = tile_n << 4;
    const int col = lane & 15, quad = lane >> 4;

    v4f acc = {0.f, 0.f, 0.f, 0.f};

    for (int k0 = 0; k0 < Kdim; k0 += 32) {
        const int ka = k0 + quad * 8;
        // A: 8 contiguous fp32 along k (two aligned float4 loads)
        const float* ap = X + (size_t)(m0 + col) * Kdim + ka;
        v4f alo = *(const v4f*)ap;
        v4f ahi = *(const v4f*)(ap + 4);
        v8s a, b;
#pragma unroll
        for (int j = 0; j < 4; ++j) { a[j] = f2bs(alo[j]); a[j + 4] = f2bs(ahi[j]); }
        // B: 8 strided fp32 (column n0+col); W is tiny -> L1/L2 resident
#pragma unroll
        for (int j = 0; j < 8; ++j)
            b[j] = f2bs(W[(size_t)(ka + j) * CC + n0 + col]);
        acc = __builtin_amdgcn_mfma_f32_16x16x32_bf16(a, b, acc, 0, 0, 0);
    }

    const float bv = bias[n0 + col];
#pragma unroll
    for (int r = 0; r < 4; ++r) {
        const int m = m0 + quad * 4 + r;
        Y[(size_t)m * CC + (n0 + col)] = acc[r] + bv;
    }
}

// ---------------------------------------------------------------------------
// Column stats: per-column sum and sum-of-squares over a row chunk, atomics.
// ---------------------------------------------------------------------------
__global__ __launch_bounds__(256)
void stat_accum_kernel(const float* __restrict__ Y, int rows_per_block,
                       float* __restrict__ sum, float* __restrict__ sumsq)
{
    const int c = threadIdx.x;
    const int r0 = blockIdx.x * rows_per_block;
    float s = 0.f, s2 = 0.f;
    for (int r = 0; r < rows_per_block; ++r) {
        const float v = Y[(size_t)(r0 + r) * CC + c];
        s += v;
        s2 = fmaf(v, v, s2);
    }
    atomicAdd(&sum[c], s);
    atomicAdd(&sumsq[c], s2);
}

// ---------------------------------------------------------------------------
// Finalize BN constants: a = g*rsqrt(var+eps), c = beta - a*mu
// sums layout: sum1[256], sq1[256], sum2[256], sq2[256]
// ac layout:   a1[256], c1[256], a2[256], c2[256]
// ---------------------------------------------------------------------------
__global__ __launch_bounds__(512)
void finalize_kernel(const float* __restrict__ sums,
                     const float* __restrict__ g1, const float* __restrict__ be1,
                     const float* __restrict__ g2, const float* __restrict__ be2,
                     float* __restrict__ ac)
{
    const int t = threadIdx.x;           // 0..511
    const int c = t & 255;
    const int which = t >> 8;            // 0: BN1, 1: BN2
    const float* s = sums + which * 512;
    const double n = which ? (double)N2R : (double)N1R;
    const double mu = (double)s[c] / n;
    const double var = (double)s[c + 256] / n - mu * mu;
    const float g  = which ? g2[c]  : g1[c];
    const float be = which ? be2[c] : be1[c];
    const double a  = (double)g / sqrt(var + 1e-5);
    const double cv = (double)be - a * mu;
    ac[which * 512 + c]       = (float)a;
    ac[which * 512 + 256 + c] = (float)cv;
}

// ---------------------------------------------------------------------------
// In-place BN + ReLU for f2 (Y2 buffer): v = max(a*v + c, 0)
// ---------------------------------------------------------------------------
__global__ __launch_bounds__(256)
void bnrelu_kernel(float* __restrict__ Y, const float* __restrict__ ac)
{
    const int idx = blockIdx.x * 256 + threadIdx.x;
    const int c = idx & 255;
    float v = Y[idx];
    Y[idx] = fmaxf(fmaf(ac[c], v, ac[256 + c]), 0.f);
}

// ---------------------------------------------------------------------------
// KNN: top-3 nearest, replicating the numpy reference's fp32 arithmetic:
//   qq  = (x*x + y*y) + z*z        products pre-rounded (array mul), no FMA
//   pp  = same
//   dot = fma(z,pz, fma(y,py, x*px))   einsum inner loop = FMA chain
//   d2  = (qq + pp) - 2.0f*dot         separate array ops, rounded stepwise
// `#pragma clang fp contract(off)` pins the non-FMA parts; fmaf is explicit.
// Selection: ascending-index scan, strict '<' == lax.top_k lowest-index ties.
// ---------------------------------------------------------------------------
__global__ __launch_bounds__(256)
void knn_kernel(const float* __restrict__ p1,
                const float* __restrict__ p2,
                int* __restrict__ idx_out, float* __restrict__ w_out)
{
#pragma clang fp contract(off)
    __shared__ float4 sp[CHUNK];   // {x, y, z, pp}

    const int row = blockIdx.x * 256 + threadIdx.x;  // block shares one batch
    const int b = row >> 14;                          // 16384 queries per batch

    const float qx = p1[(size_t)row * 3 + 0];
    const float qy = p1[(size_t)row * 3 + 1];
    const float qz = p1[(size_t)row * 3 + 2];
    const float qq = (qx * qx + qy * qy) + qz * qz;

    float b0 = 3.0e38f, b1 = 3.0e38f, b2 = 3.0e38f;
    int i0 = 0, i1 = 0, i2 = 0;

    const float* pb = p2 + (size_t)b * NPB * 3;

    for (int cb = 0; cb < NPB; cb += CHUNK) {
        __syncthreads();
        for (int t = threadIdx.x; t < CHUNK; t += 256) {
            const float x = pb[(size_t)(cb + t) * 3 + 0];
            const float y = pb[(size_t)(cb + t) * 3 + 1];
            const float z = pb[(size_t)(cb + t) * 3 + 2];
            float4 v;
            v.x = x; v.y = y; v.z = z;
            v.w = (x * x + y * y) + z * z;   // products pre-rounded, seq adds
            sp[t] = v;
        }
        __syncthreads();

#pragma unroll 4
        for (int j = 0; j < CHUNK; ++j) {
            const float4 P = sp[j];                       // wave-uniform broadcast
            const float dot = fmaf(qz, P.z, fmaf(qy, P.y, qx * P.x));
            const float d = (qq + P.w) - 2.0f * dot;
            if (d < b2) {
                const int jj = cb + j;
                if (d < b1) {
                    b2 = b1; i2 = i1;
                    if (d < b0) { b1 = b0; i1 = i0; b0 = d; i0 = jj; }
                    else        { b1 = d;  i1 = jj; }
                } else {
                    b2 = d; i2 = jj;
                }
            }
        }
    }

    // weights, mirroring numpy fp32: dist=max(d,0); r=1/(dist+1e-8); w=r/sum
    const float r0 = 1.0f / (fmaxf(b0, 0.0f) + 1e-8f);
    const float r1 = 1.0f / (fmaxf(b1, 0.0f) + 1e-8f);
    const float r2 = 1.0f / (fmaxf(b2, 0.0f) + 1e-8f);
    const float rs = (r0 + r1) + r2;

    idx_out[(size_t)row * 3 + 0] = i0;
    idx_out[(size_t)row * 3 + 1] = i1;
    idx_out[(size_t)row * 3 + 2] = i2;
    w_out[(size_t)row * 3 + 0] = r0 / rs;
    w_out[(size_t)row * 3 + 1] = r1 / rs;
    w_out[(size_t)row * 3 + 2] = r2 / rs;
}

// ---------------------------------------------------------------------------
// Final: out[row][c] = relu(a1*Y1 + c1) + sum_k w_k * f2[idx_k][c]
// Y1 lives in d_out; each thread reads its own element then overwrites it.
// ---------------------------------------------------------------------------
__global__ __launch_bounds__(256)
void final_kernel(float* __restrict__ Y1out,
                  const float* __restrict__ f2,
                  const float* __restrict__ ac,        // a1[256], c1[256]
                  const int* __restrict__ idx, const float* __restrict__ w)
{
    const int row = blockIdx.x;
    const int c = threadIdx.x;
    const int b = row >> 14;

    const float y = Y1out[(size_t)row * CC + c];
    float s = fmaxf(fmaf(ac[c], y, ac[256 + c]), 0.f);

    const int*   ir = idx + (size_t)row * 3;
    const float* wr = w   + (size_t)row * 3;
#pragma unroll
    for (int k = 0; k < 3; ++k) {
        const int id = ir[k];
        s += wr[k] * f2[((size_t)(b * NPB + id)) * CC + c];
    }
    Y1out[(size_t)row * CC + c] = s;
}

// ---------------------------------------------------------------------------
extern "C" void kernel_launch(void* const* d_in, const int* in_sizes, int n_in,
                              void* d_out, int out_size, void* d_ws, size_t ws_size,
                              hipStream_t stream)
{
    const float* point1 = (const float*)d_in[0];
    const float* feat1  = (const float*)d_in[1];
    const float* point2 = (const float*)d_in[2];
    const float* feat2  = (const float*)d_in[3];
    const float* W1     = (const float*)d_in[4];
    const float* b1     = (const float*)d_in[5];
    const float* g1     = (const float*)d_in[6];
    const float* beta1  = (const float*)d_in[7];
    const float* W2     = (const float*)d_in[8];
    const float* b2     = (const float*)d_in[9];
    const float* g2     = (const float*)d_in[10];
    const float* beta2  = (const float*)d_in[11];

    float* Y1 = (float*)d_out;                            // 64 MB (reused as output)

    char* ws = (char*)d_ws;
    float* Y2    = (float*)ws;                            // 16 MB (becomes f2 in-place)
    float* stats = (float*)(ws + (size_t)16777216);       // 1024 floats
    float* ac    = stats + 1024;                          // 1024 floats
    int*   idxb  = (int*)(ac + 1024);                     // 65536*3 ints
    float* wb    = (float*)(idxb + (size_t)N1R * 3);      // 65536*3 floats

    hipMemsetAsync(stats, 0, 1024 * sizeof(float), stream);

    // GEMMs (one wave per 16x16 tile)
    gemm_bias_kernel<<<N1R / 4, 256, 0, stream>>>(feat1, W1, b1, Y1, 256);
    gemm_bias_kernel<<<N2R / 4, 256, 0, stream>>>(feat2, W2, b2, Y2, 512);

    // BN stats (256 rows per block)
    stat_accum_kernel<<<N1R / 256, 256, 0, stream>>>(Y1, 256, stats + 0,   stats + 256);
    stat_accum_kernel<<<N2R / 256, 256, 0, stream>>>(Y2, 256, stats + 512, stats + 768);
    finalize_kernel<<<1, 512, 0, stream>>>(stats, g1, beta1, g2, beta2, ac);

    // f2 = relu(bn(Y2)) in place
    bnrelu_kernel<<<(N2R * CC) / 256, 256, 0, stream>>>(Y2, ac + 512);

    // top-3 KNN replicating numpy fp32 arithmetic + interp weights
    knn_kernel<<<N1R / 256, 256, 0, stream>>>(point1, point2, idxb, wb);

    // out = relu(bn(Y1)) + weighted gather of f2   (in-place on d_out)
    final_kernel<<<N1R, 256, 0, stream>>>(Y1, Y2, ac, idxb, wb);
}

// Round 5
// 684.570 us; speedup vs baseline: 1.2955x; 1.2955x over previous
//
#include <hip/hip_runtime.h>
#include <hip/hip_bf16.h>
#include <math.h>

// Problem constants
#define N1R 65536   // B*N1 query rows
#define N2R 16384   // B*N2 point rows
#define NPB 4096    // N2 per batch
#define CC  256     // COUT
#define SPLIT 4     // KNN point-dim split (occupancy)
#define SPTS (NPB / SPLIT)   // 1024 points per split

typedef __attribute__((ext_vector_type(4))) float v4f;
typedef __attribute__((ext_vector_type(8))) short v8s;

static __device__ __forceinline__ short f2bs(float f) {
    union { __hip_bfloat16 h; short s; } u;
    u.h = __float2bfloat16(f);
    return u.s;
}

// ---------------------------------------------------------------------------
// W transpose + bf16 convert: WT[n][k] = bf16(W[k][n]).  W: Kd x 256.
// Coalesced read, scattered write; tiny (<= 128K elements).
// ---------------------------------------------------------------------------
__global__ __launch_bounds__(256)
void wtrans_kernel(const float* __restrict__ W, short* __restrict__ WT, int Kd)
{
    const int i = blockIdx.x * 256 + threadIdx.x;   // over Kd*256
    const int k = i >> 8;
    const int n = i & 255;
    WT[(size_t)n * Kd + k] = f2bs(W[i]);
}

// ---------------------------------------------------------------------------
// GEMM: Y = X(n x Kdim, fp32) @ W(Kdim x 256) + bias, store fp32.
// B from pre-transposed bf16 WT[n][k] -> single 16B v8s load per k-step.
// A-frag: m = lane&15, k = (lane>>4)*8 + j
// B-frag: n = lane&15, k = (lane>>4)*8 + j
// D:      col n = lane&15, row m = (lane>>4)*4 + reg
// ---------------------------------------------------------------------------
__global__ __launch_bounds__(256)
void gemm_bias_kernel(const float* __restrict__ X,
                      const short* __restrict__ WT,
                      const float* __restrict__ bias,
                      float* __restrict__ Y,
                      int Kdim)
{
    const int wave = (blockIdx.x << 2) + (threadIdx.x >> 6);
    const int lane = threadIdx.x & 63;
    const int tile_m = wave >> 4;        // 16 column tiles (256/16)
    const int tile_n = wave & 15;
    const int m0 = tile_m << 4, n0 = tile_n << 4;
    const int col = lane & 15, quad = lane >> 4;

    v4f acc = {0.f, 0.f, 0.f, 0.f};
    const short* wrow = WT + (size_t)(n0 + col) * Kdim;

    for (int k0 = 0; k0 < Kdim; k0 += 32) {
        const int ka = k0 + quad * 8;
        // A: 8 contiguous fp32 along k (two aligned float4 loads) -> bf16
        const float* ap = X + (size_t)(m0 + col) * Kdim + ka;
        v4f alo = *(const v4f*)ap;
        v4f ahi = *(const v4f*)(ap + 4);
        v8s a;
#pragma unroll
        for (int j = 0; j < 4; ++j) { a[j] = f2bs(alo[j]); a[j + 4] = f2bs(ahi[j]); }
        // B: one 16B load from transposed bf16 weights
        v8s b = *(const v8s*)(wrow + ka);
        acc = __builtin_amdgcn_mfma_f32_16x16x32_bf16(a, b, acc, 0, 0, 0);
    }

    const float bv = bias[n0 + col];
#pragma unroll
    for (int r = 0; r < 4; ++r) {
        const int m = m0 + quad * 4 + r;
        Y[(size_t)m * CC + (n0 + col)] = acc[r] + bv;
    }
}

// ---------------------------------------------------------------------------
// Column stats: per-column sum and sum-of-squares over a row chunk, atomics.
// ---------------------------------------------------------------------------
__global__ __launch_bounds__(256)
void stat_accum_kernel(const float* __restrict__ Y, int rows_per_block,
                       float* __restrict__ sum, float* __restrict__ sumsq)
{
    const int c = threadIdx.x;
    const int r0 = blockIdx.x * rows_per_block;
    float s = 0.f, s2 = 0.f;
    for (int r = 0; r < rows_per_block; ++r) {
        const float v = Y[(size_t)(r0 + r) * CC + c];
        s += v;
        s2 = fmaf(v, v, s2);
    }
    atomicAdd(&sum[c], s);
    atomicAdd(&sumsq[c], s2);
}

// ---------------------------------------------------------------------------
// Finalize BN constants: a = g*rsqrt(var+eps), c = beta - a*mu
// ---------------------------------------------------------------------------
__global__ __launch_bounds__(512)
void finalize_kernel(const float* __restrict__ sums,
                     const float* __restrict__ g1, const float* __restrict__ be1,
                     const float* __restrict__ g2, const float* __restrict__ be2,
                     float* __restrict__ ac)
{
    const int t = threadIdx.x;           // 0..511
    const int c = t & 255;
    const int which = t >> 8;            // 0: BN1, 1: BN2
    const float* s = sums + which * 512;
    const double n = which ? (double)N2R : (double)N1R;
    const double mu = (double)s[c] / n;
    const double var = (double)s[c + 256] / n - mu * mu;
    const float g  = which ? g2[c]  : g1[c];
    const float be = which ? be2[c] : be1[c];
    const double a  = (double)g / sqrt(var + 1e-5);
    const double cv = (double)be - a * mu;
    ac[which * 512 + c]       = (float)a;
    ac[which * 512 + 256 + c] = (float)cv;
}

// ---------------------------------------------------------------------------
// In-place BN + ReLU for f2 (Y2 buffer): v = max(a*v + c, 0)
// ---------------------------------------------------------------------------
__global__ __launch_bounds__(256)
void bnrelu_kernel(float* __restrict__ Y, const float* __restrict__ ac)
{
    const int idx = blockIdx.x * 256 + threadIdx.x;
    const int c = idx & 255;
    float v = Y[idx];
    Y[idx] = fmaxf(fmaf(ac[c], v, ac[256 + c]), 0.f);
}

// ---------------------------------------------------------------------------
// KNN partial: per query, top-3 over ONE split of 1024 points (grid.y = split).
// Replicates numpy fp32 arithmetic (bit-exact ranking):
//   qq/pp: products pre-rounded, sequential adds, no FMA (contract off)
//   dot  : fma(z,pz, fma(y,py, x*px))  == einsum inner FMA chain
//   d    : fmaf(-2, dot, qq+pp)        == (qq+pp) - 2*dot (2*dot exact)
// Branchless sorted insert, ballot-skipped when no lane updates.
// ---------------------------------------------------------------------------
__global__ __launch_bounds__(256)
void knn_partial_kernel(const float* __restrict__ p1,
                        const float* __restrict__ p2,
                        float* __restrict__ pd, int* __restrict__ pi)
{
#pragma clang fp contract(off)
    __shared__ float4 sp[SPTS];   // {x, y, z, pp}

    const int qrow = blockIdx.x * 256 + threadIdx.x;  // block shares one batch
    const int s = blockIdx.y;                          // split id
    const int b = qrow >> 14;                          // 16384 queries per batch
    const int base = s * SPTS;

    const float qx = p1[(size_t)qrow * 3 + 0];
    const float qy = p1[(size_t)qrow * 3 + 1];
    const float qz = p1[(size_t)qrow * 3 + 2];
    const float qq = (qx * qx + qy * qy) + qz * qz;

    const float* pb = p2 + ((size_t)b * NPB + base) * 3;
    for (int t = threadIdx.x; t < SPTS; t += 256) {
        const float x = pb[(size_t)t * 3 + 0];
        const float y = pb[(size_t)t * 3 + 1];
        const float z = pb[(size_t)t * 3 + 2];
        float4 v;
        v.x = x; v.y = y; v.z = z;
        v.w = (x * x + y * y) + z * z;   // products pre-rounded, seq adds
        sp[t] = v;
    }
    __syncthreads();

    float b0 = 3.0e38f, b1 = 3.0e38f, b2 = 3.0e38f;
    int i0 = 0, i1 = 0, i2 = 0;

#pragma unroll 4
    for (int j = 0; j < SPTS; ++j) {
        const float4 P = sp[j];                       // wave-uniform broadcast
        const float dot = fmaf(qz, P.z, fmaf(qy, P.y, qx * P.x));
        const float d = fmaf(-2.0f, dot, qq + P.w);   // == (qq+pp) - 2f*dot
        const bool lt2 = d < b2;
        if (__ballot(lt2)) {
            const int jj = base + j;
            const bool lt1 = d < b1;
            const bool lt0 = d < b0;
            b2 = lt1 ? b1 : (lt2 ? d : b2);  i2 = lt1 ? i1 : (lt2 ? jj : i2);
            b1 = lt0 ? b0 : (lt1 ? d : b1);  i1 = lt0 ? i0 : (lt1 ? jj : i1);
            b0 = lt0 ? d  : b0;              i0 = lt0 ? jj : i0;
        }
    }

    const size_t o = (size_t)qrow * (SPLIT * 3) + s * 3;
    pd[o + 0] = b0; pd[o + 1] = b1; pd[o + 2] = b2;
    pi[o + 0] = i0; pi[o + 1] = i1; pi[o + 2] = i2;
}

// ---------------------------------------------------------------------------
// KNN merge: lexicographic-(d, idx) top-3 over the 12 split candidates.
// Stable-sort-by-d (== lax.top_k lowest-index ties) = min-3 by (d, idx).
// Then interpolation weights in fp32 (mirrors numpy).
// ---------------------------------------------------------------------------
__global__ __launch_bounds__(256)
void knn_merge_kernel(const float* __restrict__ pd, const int* __restrict__ pi,
                      int* __restrict__ idx_out, float* __restrict__ w_out)
{
    const int q = blockIdx.x * 256 + threadIdx.x;
    const size_t o = (size_t)q * (SPLIT * 3);

    float b0 = 3.0e38f, b1 = 3.0e38f, b2 = 3.0e38f;
    int i0 = 0x7fffffff, i1 = 0x7fffffff, i2 = 0x7fffffff;

#pragma unroll
    for (int t = 0; t < SPLIT * 3; ++t) {
        const float d = pd[o + t];
        const int jj = pi[o + t];
        const bool lt2 = (d < b2) || (d == b2 && jj < i2);
        const bool lt1 = (d < b1) || (d == b1 && jj < i1);
        const bool lt0 = (d < b0) || (d == b0 && jj < i0);
        b2 = lt1 ? b1 : (lt2 ? d : b2);  i2 = lt1 ? i1 : (lt2 ? jj : i2);
        b1 = lt0 ? b0 : (lt1 ? d : b1);  i1 = lt0 ? i0 : (lt1 ? jj : i1);
        b0 = lt0 ? d  : b0;              i0 = lt0 ? jj : i0;
    }

    const float r0 = 1.0f / (fmaxf(b0, 0.0f) + 1e-8f);
    const float r1 = 1.0f / (fmaxf(b1, 0.0f) + 1e-8f);
    const float r2 = 1.0f / (fmaxf(b2, 0.0f) + 1e-8f);
    const float rs = (r0 + r1) + r2;

    idx_out[(size_t)q * 3 + 0] = i0;
    idx_out[(size_t)q * 3 + 1] = i1;
    idx_out[(size_t)q * 3 + 2] = i2;
    w_out[(size_t)q * 3 + 0] = r0 / rs;
    w_out[(size_t)q * 3 + 1] = r1 / rs;
    w_out[(size_t)q * 3 + 2] = r2 / rs;
}

// ---------------------------------------------------------------------------
// Final: out[row][c] = relu(a1*Y1 + c1) + sum_k w_k * f2[idx_k][c]
// Y1 lives in d_out; each thread reads its own element then overwrites it.
// ---------------------------------------------------------------------------
__global__ __launch_bounds__(256)
void final_kernel(float* __restrict__ Y1out,
                  const float* __restrict__ f2,
                  const float* __restrict__ ac,        // a1[256], c1[256]
                  const int* __restrict__ idx, const float* __restrict__ w)
{
    const int row = blockIdx.x;
    const int c = threadIdx.x;
    const int b = row >> 14;

    const float y = Y1out[(size_t)row * CC + c];
    float s = fmaxf(fmaf(ac[c], y, ac[256 + c]), 0.f);

    const int*   ir = idx + (size_t)row * 3;
    const float* wr = w   + (size_t)row * 3;
#pragma unroll
    for (int k = 0; k < 3; ++k) {
        const int id = ir[k];
        s += wr[k] * f2[((size_t)(b * NPB + id)) * CC + c];
    }
    Y1out[(size_t)row * CC + c] = s;
}

// ---------------------------------------------------------------------------
extern "C" void kernel_launch(void* const* d_in, const int* in_sizes, int n_in,
                              void* d_out, int out_size, void* d_ws, size_t ws_size,
                              hipStream_t stream)
{
    const float* point1 = (const float*)d_in[0];
    const float* feat1  = (const float*)d_in[1];
    const float* point2 = (const float*)d_in[2];
    const float* feat2  = (const float*)d_in[3];
    const float* W1     = (const float*)d_in[4];
    const float* b1     = (const float*)d_in[5];
    const float* g1     = (const float*)d_in[6];
    const float* beta1  = (const float*)d_in[7];
    const float* W2     = (const float*)d_in[8];
    const float* b2     = (const float*)d_in[9];
    const float* g2     = (const float*)d_in[10];
    const float* beta2  = (const float*)d_in[11];

    float* Y1 = (float*)d_out;                            // 64 MB (reused as output)

    char* ws = (char*)d_ws;
    float* Y2    = (float*)ws;                                   // 16 MB
    float* stats = (float*)(ws + (size_t)16777216);              // 4 KB
    float* ac    = (float*)(ws + (size_t)16781312);              // 4 KB
    int*   idxb  = (int*)  (ws + (size_t)16785408);              // 768 KB
    float* wb    = (float*)(ws + (size_t)17571840);              // 768 KB
    float* pd    = (float*)(ws + (size_t)18358272);              // 3 MB
    int*   pi    = (int*)  (ws + (size_t)21504000);              // 3 MB
    short* WT1   = (short*)(ws + (size_t)24649728);              // 128 KB
    short* WT2   = (short*)(ws + (size_t)24780800);              // 256 KB

    hipMemsetAsync(stats, 0, 1024 * sizeof(float), stream);

    // Transpose+convert weights (tiny)
    wtrans_kernel<<<256, 256, 0, stream>>>(W1, WT1, 256);
    wtrans_kernel<<<512, 256, 0, stream>>>(W2, WT2, 512);

    // GEMMs (one wave per 16x16 tile)
    gemm_bias_kernel<<<N1R / 4, 256, 0, stream>>>(feat1, WT1, b1, Y1, 256);
    gemm_bias_kernel<<<N2R / 4, 256, 0, stream>>>(feat2, WT2, b2, Y2, 512);

    // BN stats (256 rows per block)
    stat_accum_kernel<<<N1R / 256, 256, 0, stream>>>(Y1, 256, stats + 0,   stats + 256);
    stat_accum_kernel<<<N2R / 256, 256, 0, stream>>>(Y2, 256, stats + 512, stats + 768);
    finalize_kernel<<<1, 512, 0, stream>>>(stats, g1, beta1, g2, beta2, ac);

    // f2 = relu(bn(Y2)) in place
    bnrelu_kernel<<<(N2R * CC) / 256, 256, 0, stream>>>(Y2, ac + 512);

    // KNN: split-4 partial scans + lexicographic merge
    knn_partial_kernel<<<dim3(N1R / 256, SPLIT), 256, 0, stream>>>(point1, point2, pd, pi);
    knn_merge_kernel<<<N1R / 256, 256, 0, stream>>>(pd, pi, idxb, wb);

    // out = relu(bn(Y1)) + weighted gather of f2   (in-place on d_out)
    final_kernel<<<N1R, 256, 0, stream>>>(Y1, Y2, ac, idxb, wb);
}

// Round 6
// 503.076 us; speedup vs baseline: 1.7628x; 1.3608x over previous
//
#include <hip/hip_runtime.h>
#include <hip/hip_bf16.h>
#include <math.h>

// Problem constants
#define N1R 65536   // B*N1 query rows
#define N2R 16384   // B*N2 point rows
#define NPB 4096    // N2 per batch
#define CC  256     // COUT
#define SPLIT 4     // KNN point-dim split (occupancy)
#define SPTS (NPB / SPLIT)   // 1024 points per split
#define ASTRIDE 40  // LDS A-tile row stride in bf16 elems (80B: 16B-aligned, ~2-way banks)

typedef __attribute__((ext_vector_type(4))) float v4f;
typedef __attribute__((ext_vector_type(8))) short v8s;

static __device__ __forceinline__ short f2bs(float f) {
    union { __hip_bfloat16 h; short s; } u;
    u.h = __float2bfloat16(f);
    return u.s;
}

// ---------------------------------------------------------------------------
// W transpose + bf16 convert: WT[n][k] = bf16(W[k][n]).  W: Kd x 256.
// ---------------------------------------------------------------------------
__global__ __launch_bounds__(256)
void wtrans_kernel(const float* __restrict__ W, short* __restrict__ WT, int Kd)
{
    const int i = blockIdx.x * 256 + threadIdx.x;   // over Kd*256
    const int k = i >> 8;
    const int n = i & 255;
    WT[(size_t)n * Kd + k] = f2bs(W[i]);
}

// ---------------------------------------------------------------------------
// Tiled GEMM: Y = X(rows x Kdim, fp32) @ W(Kdim x 256) + bias, fp32 out.
// Block = 256 thr (4 waves) computes a 128x128 tile; wave w -> 64x64 quadrant
// (wm0=(w>>1)*64, wn0=(w&1)*64) as 4x4 grid of 16x16 MFMA tiles.
// A: 128x32 fp32 chunk staged to LDS as bf16 (converted once), stride 40.
// B: v8s loads from pre-transposed bf16 WT[n][k] (L1/L2-resident).
// Frag layout (verified r4/r5): A/B k = quad*8+j, m/n = col; D row = quad*4+r.
// ---------------------------------------------------------------------------
__global__ __launch_bounds__(256)
void gemm_tile_kernel(const float* __restrict__ X,
                      const short* __restrict__ WT,
                      const float* __restrict__ bias,
                      float* __restrict__ Y,
                      int Kdim)
{
    __shared__ short As[128 * ASTRIDE];

    const int bm0 = blockIdx.x * 128;
    const int bn0 = blockIdx.y * 128;
    const int wave = threadIdx.x >> 6;
    const int lane = threadIdx.x & 63;
    const int wm0 = (wave >> 1) * 64;
    const int wn0 = (wave & 1) * 64;
    const int col = lane & 15, quad = lane >> 4;

    // staging assignment: thread t -> row t>>1, k-half (t&1)*16
    const int srow = threadIdx.x >> 1;
    const int skh  = (threadIdx.x & 1) * 16;
    const float* sbase = X + (size_t)(bm0 + srow) * Kdim + skh;
    short* sdst = As + srow * ASTRIDE + skh;

    v4f acc[4][4];
#pragma unroll
    for (int i = 0; i < 4; ++i)
#pragma unroll
        for (int j = 0; j < 4; ++j) acc[i][j] = (v4f){0.f, 0.f, 0.f, 0.f};

    const short* wbase = WT + (size_t)(bn0 + wn0 + col) * Kdim + quad * 8;

    for (int k0 = 0; k0 < Kdim; k0 += 32) {
        __syncthreads();   // previous iteration's LDS reads done
        // stage 16 floats -> 16 bf16 (two v8s)
        const float* sp = sbase + k0;
        v4f f0 = *(const v4f*)sp;
        v4f f1 = *(const v4f*)(sp + 4);
        v4f f2 = *(const v4f*)(sp + 8);
        v4f f3 = *(const v4f*)(sp + 12);
        v8s lo, hi;
#pragma unroll
        for (int j = 0; j < 4; ++j) {
            lo[j] = f2bs(f0[j]); lo[j + 4] = f2bs(f1[j]);
            hi[j] = f2bs(f2[j]); hi[j + 4] = f2bs(f3[j]);
        }
        *(v8s*)sdst = lo;
        *(v8s*)(sdst + 8) = hi;
        __syncthreads();

        v8s a[4], bf[4];
#pragma unroll
        for (int mi = 0; mi < 4; ++mi)
            a[mi] = *(const v8s*)(As + (wm0 + mi * 16 + col) * ASTRIDE + quad * 8);
#pragma unroll
        for (int ni = 0; ni < 4; ++ni)
            bf[ni] = *(const v8s*)(wbase + (size_t)(ni * 16) * Kdim + k0);
#pragma unroll
        for (int mi = 0; mi < 4; ++mi)
#pragma unroll
            for (int ni = 0; ni < 4; ++ni)
                acc[mi][ni] = __builtin_amdgcn_mfma_f32_16x16x32_bf16(a[mi], bf[ni], acc[mi][ni], 0, 0, 0);
    }

    // epilogue: bias + store fp32
#pragma unroll
    for (int ni = 0; ni < 4; ++ni) {
        const int n = bn0 + wn0 + ni * 16 + col;
        const float bv = bias[n];
#pragma unroll
        for (int mi = 0; mi < 4; ++mi) {
            const int m = bm0 + wm0 + mi * 16 + quad * 4;
#pragma unroll
            for (int r = 0; r < 4; ++r)
                Y[(size_t)(m + r) * CC + n] = acc[mi][ni][r] + bv;
        }
    }
}

// ---------------------------------------------------------------------------
// Column stats: per-column sum and sum-of-squares over a row chunk, atomics.
// ---------------------------------------------------------------------------
__global__ __launch_bounds__(256)
void stat_accum_kernel(const float* __restrict__ Y, int rows_per_block,
                       float* __restrict__ sum, float* __restrict__ sumsq)
{
    const int c = threadIdx.x;
    const int r0 = blockIdx.x * rows_per_block;
    float s = 0.f, s2 = 0.f;
    for (int r = 0; r < rows_per_block; ++r) {
        const float v = Y[(size_t)(r0 + r) * CC + c];
        s += v;
        s2 = fmaf(v, v, s2);
    }
    atomicAdd(&sum[c], s);
    atomicAdd(&sumsq[c], s2);
}

// ---------------------------------------------------------------------------
// Finalize BN constants: a = g*rsqrt(var+eps), c = beta - a*mu
// ---------------------------------------------------------------------------
__global__ __launch_bounds__(512)
void finalize_kernel(const float* __restrict__ sums,
                     const float* __restrict__ g1, const float* __restrict__ be1,
                     const float* __restrict__ g2, const float* __restrict__ be2,
                     float* __restrict__ ac)
{
    const int t = threadIdx.x;           // 0..511
    const int c = t & 255;
    const int which = t >> 8;            // 0: BN1, 1: BN2
    const float* s = sums + which * 512;
    const double n = which ? (double)N2R : (double)N1R;
    const double mu = (double)s[c] / n;
    const double var = (double)s[c + 256] / n - mu * mu;
    const float g  = which ? g2[c]  : g1[c];
    const float be = which ? be2[c] : be1[c];
    const double a  = (double)g / sqrt(var + 1e-5);
    const double cv = (double)be - a * mu;
    ac[which * 512 + c]       = (float)a;
    ac[which * 512 + 256 + c] = (float)cv;
}

// ---------------------------------------------------------------------------
// In-place BN + ReLU for f2 (Y2 buffer): v = max(a*v + c, 0)
// ---------------------------------------------------------------------------
__global__ __launch_bounds__(256)
void bnrelu_kernel(float* __restrict__ Y, const float* __restrict__ ac)
{
    const int idx = blockIdx.x * 256 + threadIdx.x;
    const int c = idx & 255;
    float v = Y[idx];
    Y[idx] = fmaxf(fmaf(ac[c], v, ac[256 + c]), 0.f);
}

// ---------------------------------------------------------------------------
// KNN partial: per query, top-3 over ONE split of 1024 points (grid.y = split).
// Replicates numpy fp32 arithmetic (bit-exact ranking):
//   qq/pp: products pre-rounded, sequential adds, no FMA (contract off)
//   dot  : fma(z,pz, fma(y,py, x*px))  == einsum inner FMA chain
//   d    : fmaf(-2, dot, qq+pp)        == (qq+pp) - 2*dot (2*dot exact)
// ---------------------------------------------------------------------------
__global__ __launch_bounds__(256)
void knn_partial_kernel(const float* __restrict__ p1,
                        const float* __restrict__ p2,
                        float* __restrict__ pd, int* __restrict__ pi)
{
#pragma clang fp contract(off)
    __shared__ float4 sp[SPTS];   // {x, y, z, pp}

    const int qrow = blockIdx.x * 256 + threadIdx.x;  // block shares one batch
    const int s = blockIdx.y;                          // split id
    const int b = qrow >> 14;                          // 16384 queries per batch
    const int base = s * SPTS;

    const float qx = p1[(size_t)qrow * 3 + 0];
    const float qy = p1[(size_t)qrow * 3 + 1];
    const float qz = p1[(size_t)qrow * 3 + 2];
    const float qq = (qx * qx + qy * qy) + qz * qz;

    const float* pb = p2 + ((size_t)b * NPB + base) * 3;
    for (int t = threadIdx.x; t < SPTS; t += 256) {
        const float x = pb[(size_t)t * 3 + 0];
        const float y = pb[(size_t)t * 3 + 1];
        const float z = pb[(size_t)t * 3 + 2];
        float4 v;
        v.x = x; v.y = y; v.z = z;
        v.w = (x * x + y * y) + z * z;   // products pre-rounded, seq adds
        sp[t] = v;
    }
    __syncthreads();

    float b0 = 3.0e38f, b1 = 3.0e38f, b2 = 3.0e38f;
    int i0 = 0, i1 = 0, i2 = 0;

#pragma unroll 4
    for (int j = 0; j < SPTS; ++j) {
        const float4 P = sp[j];                       // wave-uniform broadcast
        const float dot = fmaf(qz, P.z, fmaf(qy, P.y, qx * P.x));
        const float d = fmaf(-2.0f, dot, qq + P.w);   // == (qq+pp) - 2f*dot
        const bool lt2 = d < b2;
        if (__ballot(lt2)) {
            const int jj = base + j;
            const bool lt1 = d < b1;
            const bool lt0 = d < b0;
            b2 = lt1 ? b1 : (lt2 ? d : b2);  i2 = lt1 ? i1 : (lt2 ? jj : i2);
            b1 = lt0 ? b0 : (lt1 ? d : b1);  i1 = lt0 ? i0 : (lt1 ? jj : i1);
            b0 = lt0 ? d  : b0;              i0 = lt0 ? jj : i0;
        }
    }

    const size_t o = (size_t)qrow * (SPLIT * 3) + s * 3;
    pd[o + 0] = b0; pd[o + 1] = b1; pd[o + 2] = b2;
    pi[o + 0] = i0; pi[o + 1] = i1; pi[o + 2] = i2;
}

// ---------------------------------------------------------------------------
// KNN merge: lexicographic-(d, idx) top-3 over the 12 split candidates.
// ---------------------------------------------------------------------------
__global__ __launch_bounds__(256)
void knn_merge_kernel(const float* __restrict__ pd, const int* __restrict__ pi,
                      int* __restrict__ idx_out, float* __restrict__ w_out)
{
    const int q = blockIdx.x * 256 + threadIdx.x;
    const size_t o = (size_t)q * (SPLIT * 3);

    float b0 = 3.0e38f, b1 = 3.0e38f, b2 = 3.0e38f;
    int i0 = 0x7fffffff, i1 = 0x7fffffff, i2 = 0x7fffffff;

#pragma unroll
    for (int t = 0; t < SPLIT * 3; ++t) {
        const float d = pd[o + t];
        const int jj = pi[o + t];
        const bool lt2 = (d < b2) || (d == b2 && jj < i2);
        const bool lt1 = (d < b1) || (d == b1 && jj < i1);
        const bool lt0 = (d < b0) || (d == b0 && jj < i0);
        b2 = lt1 ? b1 : (lt2 ? d : b2);  i2 = lt1 ? i1 : (lt2 ? jj : i2);
        b1 = lt0 ? b0 : (lt1 ? d : b1);  i1 = lt0 ? i0 : (lt1 ? jj : i1);
        b0 = lt0 ? d  : b0;              i0 = lt0 ? jj : i0;
    }

    const float r0 = 1.0f / (fmaxf(b0, 0.0f) + 1e-8f);
    const float r1 = 1.0f / (fmaxf(b1, 0.0f) + 1e-8f);
    const float r2 = 1.0f / (fmaxf(b2, 0.0f) + 1e-8f);
    const float rs = (r0 + r1) + r2;

    idx_out[(size_t)q * 3 + 0] = i0;
    idx_out[(size_t)q * 3 + 1] = i1;
    idx_out[(size_t)q * 3 + 2] = i2;
    w_out[(size_t)q * 3 + 0] = r0 / rs;
    w_out[(size_t)q * 3 + 1] = r1 / rs;
    w_out[(size_t)q * 3 + 2] = r2 / rs;
}

// ---------------------------------------------------------------------------
// Final: out[row][c] = relu(a1*Y1 + c1) + sum_k w_k * f2[idx_k][c]
// ---------------------------------------------------------------------------
__global__ __launch_bounds__(256)
void final_kernel(float* __restrict__ Y1out,
                  const float* __restrict__ f2,
                  const float* __restrict__ ac,        // a1[256], c1[256]
                  const int* __restrict__ idx, const float* __restrict__ w)
{
    const int row = blockIdx.x;
    const int c = threadIdx.x;
    const int b = row >> 14;

    const float y = Y1out[(size_t)row * CC + c];
    float s = fmaxf(fmaf(ac[c], y, ac[256 + c]), 0.f);

    const int*   ir = idx + (size_t)row * 3;
    const float* wr = w   + (size_t)row * 3;
#pragma unroll
    for (int k = 0; k < 3; ++k) {
        const int id = ir[k];
        s += wr[k] * f2[((size_t)(b * NPB + id)) * CC + c];
    }
    Y1out[(size_t)row * CC + c] = s;
}

// ---------------------------------------------------------------------------
extern "C" void kernel_launch(void* const* d_in, const int* in_sizes, int n_in,
                              void* d_out, int out_size, void* d_ws, size_t ws_size,
                              hipStream_t stream)
{
    const float* point1 = (const float*)d_in[0];
    const float* feat1  = (const float*)d_in[1];
    const float* point2 = (const float*)d_in[2];
    const float* feat2  = (const float*)d_in[3];
    const float* W1     = (const float*)d_in[4];
    const float* b1     = (const float*)d_in[5];
    const float* g1     = (const float*)d_in[6];
    const float* beta1  = (const float*)d_in[7];
    const float* W2     = (const float*)d_in[8];
    const float* b2     = (const float*)d_in[9];
    const float* g2     = (const float*)d_in[10];
    const float* beta2  = (const float*)d_in[11];

    float* Y1 = (float*)d_out;                            // 64 MB (reused as output)

    char* ws = (char*)d_ws;
    float* Y2    = (float*)ws;                                   // 16 MB
    float* stats = (float*)(ws + (size_t)16777216);              // 4 KB
    float* ac    = (float*)(ws + (size_t)16781312);              // 4 KB
    int*   idxb  = (int*)  (ws + (size_t)16785408);              // 768 KB
    float* wb    = (float*)(ws + (size_t)17571840);              // 768 KB
    float* pd    = (float*)(ws + (size_t)18358272);              // 3 MB
    int*   pi    = (int*)  (ws + (size_t)21504000);              // 3 MB
    short* WT1   = (short*)(ws + (size_t)24649728);              // 128 KB
    short* WT2   = (short*)(ws + (size_t)24780800);              // 256 KB

    hipMemsetAsync(stats, 0, 1024 * sizeof(float), stream);

    // Transpose+convert weights (tiny)
    wtrans_kernel<<<256, 256, 0, stream>>>(W1, WT1, 256);
    wtrans_kernel<<<512, 256, 0, stream>>>(W2, WT2, 512);

    // Tiled GEMMs: grid = (rows/128, 256/128)
    gemm_tile_kernel<<<dim3(N1R / 128, 2), 256, 0, stream>>>(feat1, WT1, b1, Y1, 256);
    gemm_tile_kernel<<<dim3(N2R / 128, 2), 256, 0, stream>>>(feat2, WT2, b2, Y2, 512);

    // BN stats (256 rows per block)
    stat_accum_kernel<<<N1R / 256, 256, 0, stream>>>(Y1, 256, stats + 0,   stats + 256);
    stat_accum_kernel<<<N2R / 256, 256, 0, stream>>>(Y2, 256, stats + 512, stats + 768);
    finalize_kernel<<<1, 512, 0, stream>>>(stats, g1, beta1, g2, beta2, ac);

    // f2 = relu(bn(Y2)) in place
    bnrelu_kernel<<<(N2R * CC) / 256, 256, 0, stream>>>(Y2, ac + 512);

    // KNN: split-4 partial scans + lexicographic merge
    knn_partial_kernel<<<dim3(N1R / 256, SPLIT), 256, 0, stream>>>(point1, point2, pd, pi);
    knn_merge_kernel<<<N1R / 256, 256, 0, stream>>>(pd, pi, idxb, wb);

    // out = relu(bn(Y1)) + weighted gather of f2   (in-place on d_out)
    final_kernel<<<N1R, 256, 0, stream>>>(Y1, Y2, ac, idxb, wb);
}